// Round 1
// baseline (457.475 us; speedup 1.0000x reference)
//
#include <hip/hip_runtime.h>

#define B_ 256
#define T_ 1024
#define V_ 5000
#define D_ 100
#define H_ 64
#define C_ 2

// ---------------------------------------------------------------------------
// Kernel 1: EW[v][h] = sum_d E[v][d] * W[d][h] + b[h]
// One thread per (v,h). W reads are coalesced across lanes (h = lane),
// E row reads are wave-uniform broadcasts (L1-served).
// ---------------------------------------------------------------------------
__global__ __launch_bounds__(256) void ew_kernel(const float* __restrict__ E,
                                                 const float* __restrict__ W,
                                                 const float* __restrict__ bias,
                                                 float* __restrict__ EW) {
    int idx = blockIdx.x * 256 + threadIdx.x;   // 0 .. V_*H_
    if (idx >= V_ * H_) return;
    int h = idx & (H_ - 1);
    int v = idx >> 6;
    float acc = bias[h];
    const float* Erow = E + v * D_;
    #pragma unroll 4
    for (int d = 0; d < D_; ++d) {
        acc = fmaf(Erow[d], W[d * H_ + h], acc);
    }
    EW[idx] = acc;
}

// ---------------------------------------------------------------------------
// Kernel 2: per-batch RNN. One wave (64 lanes) per batch element.
// Lane j holds h[j], U[:,j] in registers, and the running pooled sum.
// Cross-lane broadcast of h[i] via v_readlane (constant lane index).
// xw gather from EW (L2-resident) software-pipelined one step ahead.
// ---------------------------------------------------------------------------
__device__ __forceinline__ float readlane_f(float v, int lane) {
    return __uint_as_float(__builtin_amdgcn_readlane(__float_as_uint(v), lane));
}

__global__ __launch_bounds__(64) void rnn_kernel(const int* __restrict__ tokens,
                                                 const float* __restrict__ EW,
                                                 const float* __restrict__ U,
                                                 const float* __restrict__ Wd,
                                                 const float* __restrict__ bd,
                                                 float* __restrict__ out) {
    const int b = blockIdx.x;     // batch element
    const int j = threadIdx.x;    // 0..63 : hidden unit

    // U column j into registers: Ucol[i] = U[i][j]  (coalesced across lanes)
    float Ucol[H_];
    #pragma unroll
    for (int i = 0; i < H_; ++i) Ucol[i] = U[i * H_ + j];

    const int* tok = tokens + b * T_;

    float h = 0.f;
    float pooled = 0.f;

    // token chunk: lane l holds tok[chunk*64 + l]; refreshed every 64 steps
    int tchunk = tok[j];
    int cur_tok = __builtin_amdgcn_readlane(tchunk, 0);
    float xw = EW[cur_tok * H_ + j];   // prefetched xw for step 0

    for (int t = 0; t < T_; ++t) {
        // ---- prefetch step t+1 (overlaps with the dot below) ----
        int nt = t + 1;
        int next_tok = 0;
        float xw_next = 0.f;
        if (nt < T_) {
            if ((nt & 63) == 0) tchunk = tok[nt + j];       // uniform branch
            next_tok = __builtin_amdgcn_readlane(tchunk, nt & 63);
            xw_next = EW[next_tok * H_ + j];                // coalesced, L2-hit
        }

        // ---- dot: x = xw + sum_i h[i] * U[i][j] ----
        float a0 = xw, a1 = 0.f, a2 = 0.f, a3 = 0.f;
        #pragma unroll
        for (int i = 0; i < H_; i += 4) {
            a0 = fmaf(readlane_f(h, i + 0), Ucol[i + 0], a0);
            a1 = fmaf(readlane_f(h, i + 1), Ucol[i + 1], a1);
            a2 = fmaf(readlane_f(h, i + 2), Ucol[i + 2], a2);
            a3 = fmaf(readlane_f(h, i + 3), Ucol[i + 3], a3);
        }
        float x = (a0 + a1) + (a2 + a3);

        // ---- fast tanh: (e^{2x}-1)/(e^{2x}+1), clamped (tanh saturates ~9) ----
        x = fminf(fmaxf(x, -15.f), 15.f);
        float e = __expf(2.f * x);
        float hn = (e - 1.f) / (e + 1.f);

        // Keras mask_zero: masked step carries previous state (uniform select)
        h = (cur_tok != 0) ? hn : h;
        pooled += h;   // unmasked mean over time: every step contributes

        cur_tok = next_tok;
        xw = xw_next;
    }

    // ---- epilogue: pooled mean -> dense(2) -> sigmoid ----
    float p = pooled * (1.0f / (float)T_);
    float v0 = p * Wd[j * C_ + 0];
    float v1 = p * Wd[j * C_ + 1];
    #pragma unroll
    for (int off = 32; off >= 1; off >>= 1) {
        v0 += __shfl_down(v0, off, 64);
        v1 += __shfl_down(v1, off, 64);
    }
    if (j == 0) {
        float l0 = v0 + bd[0];
        float l1 = v1 + bd[1];
        out[b * C_ + 0] = 1.f / (1.f + __expf(-l0));
        out[b * C_ + 1] = 1.f / (1.f + __expf(-l1));
    }
}

// ---------------------------------------------------------------------------
extern "C" void kernel_launch(void* const* d_in, const int* in_sizes, int n_in,
                              void* d_out, int out_size, void* d_ws, size_t ws_size,
                              hipStream_t stream) {
    const int*   tokens = (const int*)  d_in[0];  // [B,T] int32
    const float* E      = (const float*)d_in[1];  // [V,D]
    const float* W      = (const float*)d_in[2];  // [D,H]
    const float* U      = (const float*)d_in[3];  // [H,H]
    const float* bias   = (const float*)d_in[4];  // [H]
    const float* Wd     = (const float*)d_in[5];  // [H,C]
    const float* bd     = (const float*)d_in[6];  // [C]
    float* out = (float*)d_out;                   // [B,C]
    float* EW  = (float*)d_ws;                    // [V,H] scratch: 1.28 MB

    ew_kernel<<<(V_ * H_ + 255) / 256, 256, 0, stream>>>(E, W, bias, EW);
    rnn_kernel<<<B_, H_, 0, stream>>>(tokens, EW, U, Wd, bd, out);
}

// Round 2
// 429.748 us; speedup vs baseline: 1.0645x; 1.0645x over previous
//
#include <hip/hip_runtime.h>

#define B_ 256
#define T_ 1024
#define V_ 5000
#define D_ 100
#define H_ 64
#define C_ 2

// ---------------------------------------------------------------------------
// Kernel 1: EW[v][h] = sum_d E[v][d] * W[d][h] + b[h]
// ---------------------------------------------------------------------------
__global__ __launch_bounds__(256) void ew_kernel(const float* __restrict__ E,
                                                 const float* __restrict__ W,
                                                 const float* __restrict__ bias,
                                                 float* __restrict__ EW) {
    int idx = blockIdx.x * 256 + threadIdx.x;   // 0 .. V_*H_
    if (idx >= V_ * H_) return;
    int h = idx & (H_ - 1);
    int v = idx >> 6;
    float acc = bias[h];
    const float* Erow = E + v * D_;
    #pragma unroll 4
    for (int d = 0; d < D_; ++d) {
        acc = fmaf(Erow[d], W[d * H_ + h], acc);
    }
    EW[idx] = acc;
}

// ---------------------------------------------------------------------------
// Kernel 2: per-batch RNN. One wave (64 lanes) per batch element.
// Lane j holds h[j], U[:,j] in registers (forced — see `one` launder below),
// cross-lane broadcast of h[i] via v_readlane (constant lane index).
// ---------------------------------------------------------------------------
__device__ __forceinline__ float readlane_f(float v, int lane) {
    return __uint_as_float(__builtin_amdgcn_readlane(__float_as_uint(v), lane));
}

__global__ __launch_bounds__(64) void rnn_kernel(const int* __restrict__ tokens,
                                                 const float* __restrict__ EW,
                                                 const float* __restrict__ U,
                                                 const float* __restrict__ Wd,
                                                 const float* __restrict__ bd,
                                                 float* __restrict__ out) {
    const int b = blockIdx.x;     // batch element
    const int j = threadIdx.x;    // 0..63 : hidden unit

    // Opaque 1.0f: compiler cannot fold it, so Ucol[i] = U[..]*one is a
    // computed value that CANNOT be rematerialized by re-loading U inside
    // the loop. This forces the 64 U-column values to stay in VGPRs.
    // (R1 post-mortem: without this, VGPR_Count=40 and the compiler
    //  re-loaded all of U every timestep -> 4.3 GB of FETCH, 915 cyc/step.)
    float one;
    asm volatile("v_mov_b32 %0, 1.0" : "=v"(one));

    float Ucol[H_];
    #pragma unroll
    for (int i = 0; i < H_; ++i) Ucol[i] = U[i * H_ + j] * one;

    const int* tok = tokens + b * T_;

    float h = 0.f;
    float pooled = 0.f;

    // token chunk: lane l holds tok[chunk*64 + l]; refreshed every 64 steps
    int tchunk = tok[j];
    int cur_tok = __builtin_amdgcn_readlane(tchunk, 0);
    float xw = EW[cur_tok * H_ + j];   // prefetched xw for step 0

    for (int t = 0; t < T_; ++t) {
        // ---- prefetch step t+1 (overlaps with the dot below) ----
        int nt = t + 1;
        int next_tok = 0;
        float xw_next = 0.f;
        if (nt < T_) {
            if ((nt & 63) == 0) tchunk = tok[nt + j];       // uniform branch
            next_tok = __builtin_amdgcn_readlane(tchunk, nt & 63);
            xw_next = EW[next_tok * H_ + j];                // coalesced, L2-hit
        }

        // ---- dot: sum_i h[i] * U[i][j], 4 independent fma chains ----
        float a0 = 0.f, a1 = 0.f, a2 = 0.f, a3 = 0.f;
        #pragma unroll
        for (int i = 0; i < H_; i += 4) {
            a0 = fmaf(readlane_f(h, i + 0), Ucol[i + 0], a0);
            a1 = fmaf(readlane_f(h, i + 1), Ucol[i + 1], a1);
            a2 = fmaf(readlane_f(h, i + 2), Ucol[i + 2], a2);
            a3 = fmaf(readlane_f(h, i + 3), Ucol[i + 3], a3);
        }
        // xw added last: dot starts without waiting on the gather's vmcnt
        float x = ((a0 + a1) + (a2 + a3)) + xw;

        // ---- fast tanh: (e^{2x}-1)*rcp(e^{2x}+1), clamped ----
        x = fminf(fmaxf(x, -15.f), 15.f);
        float e = __expf(2.f * x);
        float hn = (e - 1.f) * __builtin_amdgcn_rcpf(e + 1.f);

        // Keras mask_zero: masked step carries previous state
        h = (cur_tok != 0) ? hn : h;
        pooled += h;   // unmasked mean over time

        cur_tok = next_tok;
        xw = xw_next;
    }

    // ---- epilogue: pooled mean -> dense(2) -> sigmoid ----
    float p = pooled * (1.0f / (float)T_);
    float v0 = p * Wd[j * C_ + 0];
    float v1 = p * Wd[j * C_ + 1];
    #pragma unroll
    for (int off = 32; off >= 1; off >>= 1) {
        v0 += __shfl_down(v0, off, 64);
        v1 += __shfl_down(v1, off, 64);
    }
    if (j == 0) {
        float l0 = v0 + bd[0];
        float l1 = v1 + bd[1];
        out[b * C_ + 0] = 1.f / (1.f + __expf(-l0));
        out[b * C_ + 1] = 1.f / (1.f + __expf(-l1));
    }
}

// ---------------------------------------------------------------------------
extern "C" void kernel_launch(void* const* d_in, const int* in_sizes, int n_in,
                              void* d_out, int out_size, void* d_ws, size_t ws_size,
                              hipStream_t stream) {
    const int*   tokens = (const int*)  d_in[0];  // [B,T] int32
    const float* E      = (const float*)d_in[1];  // [V,D]
    const float* W      = (const float*)d_in[2];  // [D,H]
    const float* U      = (const float*)d_in[3];  // [H,H]
    const float* bias   = (const float*)d_in[4];  // [H]
    const float* Wd     = (const float*)d_in[5];  // [H,C]
    const float* bd     = (const float*)d_in[6];  // [C]
    float* out = (float*)d_out;                   // [B,C]
    float* EW  = (float*)d_ws;                    // [V,H] scratch: 1.28 MB

    ew_kernel<<<(V_ * H_ + 255) / 256, 256, 0, stream>>>(E, W, bias, EW);
    rnn_kernel<<<B_, H_, 0, stream>>>(tokens, EW, U, Wd, bd, out);
}